// Round 7
// baseline (564.512 us; speedup 1.0000x reference)
//
#include <hip/hip_runtime.h>
#include <hip/hip_bf16.h>
#include <stdint.h>

// GINE net, MI355X. Pipeline (R7):
//   k_setup  : piecewise-linear edge-MLP coeffs ABp[65][64] (packed bf16 A|B<<16) +
//              SORTED thresholds tsS[64] (+inf padded)
//   k_cast   : f32 -> bf16 node-feature gather table
//   CSR build (radix by dst>>9, 512-node buckets; R6's 128-node buckets caused 9x
//   write amplification in k_bpart -- 2-edge runs = partial 64B lines cross-XCD):
//     k_bcount -> k_bscan -> k_bpart (int2 stage + u16 dstl) -> k_blocal (512/block)
//   k_conv   : u = bf16((1+eps)*bf16(x) + sum relu(bf16(x[src]) + a*A_p + B_p));
//              explicit payload prefetch pipeline (qc/qn), launch_bounds(256,6)
//   k_mlp    : weights-in-registers node-streaming MLP: wave=node, lane=out feature,
//              W cols in 128 VGPRs, u-row broadcast via per-wave LDS row.
//              (R6's thread-per-node form issued ~16K wave-uniform loads/thread ->
//              suspected ~60us each, hidden below profiler top-5 cutoff.)
//   k_classify: logits + log_softmax

typedef unsigned int uint32;
typedef unsigned short ushort16;

static __device__ __forceinline__ unsigned short f2bf(float f) {
  __hip_bfloat16 h = __float2bfloat16(f);
  return *reinterpret_cast<unsigned short*>(&h);
}
static __device__ __forceinline__ float bf2f(unsigned short u) {
  return __uint_as_float(((uint32)u) << 16);
}

// One block per piece p (65 blocks). w2/b2 staged in LDS. Block 0 additionally emits
// sorted thresholds tsS (ascending; invalid units -> +inf at the tail).
__global__ __launch_bounds__(256) void k_setup(
    const float* __restrict__ w1, const float* __restrict__ b1,
    const float* __restrict__ w2, const float* __restrict__ b2,
    float* __restrict__ tsS, uint32* __restrict__ ABp) {
  __shared__ float w2s[64 * 64];
  __shared__ float b2s[64];
  __shared__ float w1s[64], b1s[64], ts[64];
  __shared__ int rs[64], ms[64], vs[64];
  const int tid = threadIdx.x;
  const int p = blockIdx.x;
  {
    const float4* g4 = (const float4*)w2;
    float4* s4 = (float4*)w2s;
    for (int i = tid; i < 64 * 16; i += 256) s4[i] = g4[i];
    if (tid < 64) b2s[tid] = b2[tid];
  }
  if (tid < 64) {
    float w = w1[tid], b = b1[tid];
    w1s[tid] = w; b1s[tid] = b;
    int v = (w != 0.0f);
    vs[tid] = v;
    ts[tid] = v ? (-b / w) : 0.0f;
  }
  __syncthreads();
  if (tid < 64) {
    float tk = ts[tid];
    int r = 0, m = 0;
    for (int k = 0; k < 64; ++k) if (vs[k]) { r += (ts[k] < tk) ? 1 : 0; m += (ts[k] == tk) ? 1 : 0; }
    rs[tid] = r; ms[tid] = m;
    if (p == 0) {
      int pos;
      if (vs[tid]) {
        int c = 0;
        for (int j = 0; j < 64; ++j)
          if (vs[j] && (ts[j] < tk || (ts[j] == tk && j < tid))) c++;
        pos = c;
      } else {
        int c = 0;
        for (int j = 0; j < 64; ++j) if (vs[j]) c++;
        for (int j = 0; j < tid; ++j) if (!vs[j]) c++;
        pos = c;
      }
      tsS[pos] = vs[tid] ? tk : __builtin_inff();
    }
  }
  __syncthreads();
  // piece p = #{thresholds < a}. Unit k active at piece p:
  //   w1>0: p >= r_k+m_k ; w1<0: p <= r_k ; w1==0: b1>0
  if (tid < 64) {
    const int j = tid;
    float accA = 0.0f, accB = b2s[j];
    for (int k = 0; k < 64; ++k) {
      bool act;
      if (vs[k]) act = (w1s[k] > 0.0f) ? (p >= rs[k] + ms[k]) : (p <= rs[k]);
      else       act = (b1s[k] > 0.0f);
      if (act) { float wv = w2s[k * 64 + j]; accA = fmaf(w1s[k], wv, accA); accB = fmaf(b1s[k], wv, accB); }
    }
    ABp[p * 64 + j] = (uint32)f2bf(accA) | ((uint32)f2bf(accB) << 16);
  }
}

__global__ void k_cast(const float* __restrict__ in, ushort16* __restrict__ out, int n4) {
  int i = blockIdx.x * blockDim.x + threadIdx.x;
  if (i >= n4) return;
  float4 v = ((const float4*)in)[i];
  ushort4 o;
  o.x = f2bf(v.x); o.y = f2bf(v.y); o.z = f2bf(v.z); o.w = f2bf(v.w);
  ((ushort4*)out)[i] = o;
}

// Inline width detection: odd 32-bit words of edge_index are int64 high-halves
// (all zero, idx < 2^20) or int32 src values (~never 64 consecutive zeros).
static __device__ __forceinline__ bool detect_is64(const uint32* ei, int E, int tid, int* sflag) {
  if (tid < 64) {
    int lim = (E < 64) ? E : 64;
    int nz = (tid < lim) ? (ei[2 * (size_t)tid + 1] != 0u) : 0;
    nz = __any(nz);
    if (tid == 0) *sflag = !nz;
  }
  __syncthreads();
  return *sflag != 0;
}

// ---- CSR build: radix partition by dst>>9 (512-node buckets) ----

__global__ __launch_bounds__(256) void k_bcount(
    const uint32* __restrict__ ei, int* __restrict__ hist1, int E) {
  __shared__ int h[1024];
  __shared__ int sIs64;
  for (int i = threadIdx.x; i < 1024; i += 256) h[i] = 0;
  bool is64 = detect_is64(ei, E, threadIdx.x, &sIs64);  // has __syncthreads
  for (int i = blockIdx.x * blockDim.x + threadIdx.x; i < E; i += gridDim.x * blockDim.x) {
    int dst = is64 ? (int)ei[2 * ((size_t)E + i)] : (int)ei[(size_t)E + i];
    atomicAdd(&h[dst >> 9], 1);
  }
  __syncthreads();
  for (int i = threadIdx.x; i < 1024; i += 256)
    if (h[i]) atomicAdd(&hist1[i], h[i]);
}

__global__ __launch_bounds__(256) void k_bscan(
    const int* __restrict__ hist1, int* __restrict__ bOffs, int* __restrict__ bCur,
    int* __restrict__ offs, int N, int E) {
  __shared__ int psum[256];
  const int tid = threadIdx.x;
  int v0 = hist1[tid * 4 + 0], v1 = hist1[tid * 4 + 1];
  int v2 = hist1[tid * 4 + 2], v3 = hist1[tid * 4 + 3];
  int sum = v0 + v1 + v2 + v3;
  psum[tid] = sum;
  __syncthreads();
  for (int d = 1; d < 256; d <<= 1) {
    int add = (tid >= d) ? psum[tid - d] : 0;
    __syncthreads();
    psum[tid] += add;
    __syncthreads();
  }
  int run = psum[tid] - sum;  // exclusive
  bOffs[tid * 4 + 0] = run; bCur[tid * 4 + 0] = run; run += v0;
  bOffs[tid * 4 + 1] = run; bCur[tid * 4 + 1] = run; run += v1;
  bOffs[tid * 4 + 2] = run; bCur[tid * 4 + 2] = run; run += v2;
  bOffs[tid * 4 + 3] = run; bCur[tid * 4 + 3] = run; run += v3;
  if (tid == 255) bOffs[1024] = run;  // == E
  if (tid == 0) offs[N] = E;
}

// tile = 2048 edges/block, 8 per thread. Ranks via LDS atomics; one global atomic
// per (block, nonempty bucket). With 512-node buckets, per-(block,bucket) runs
// average ~10 edges -> ~83B contiguous int2 writes (R6's 128-node buckets: 2-edge
// runs, 129MB WRITE_SIZE from partial-line cross-XCD stores).
__global__ __launch_bounds__(256) void k_bpart(
    const uint32* __restrict__ ei, const float* __restrict__ ea,
    const float* __restrict__ tsSg, int* __restrict__ bCur,
    int2* __restrict__ stage, unsigned short* __restrict__ dstw, int E) {
  __shared__ int cnt[1024];
  __shared__ float tss[64];
  __shared__ int sIs64;
  const int tid = threadIdx.x;
  for (int i = tid; i < 1024; i += 256) cnt[i] = 0;
  if (tid >= 64 && tid < 128) tss[tid - 64] = tsSg[tid - 64];
  bool is64 = detect_is64(ei, E, tid, &sIs64);  // has __syncthreads
  const int base0 = blockIdx.x * 2048;
  int dstv[8], srcv[8], rk[8];
  float av[8];
#pragma unroll
  for (int e = 0; e < 8; ++e) {
    int idx = base0 + e * 256 + tid;
    if (idx < E) {
      int src, dst;
      if (is64) { src = (int)ei[2 * (size_t)idx]; dst = (int)ei[2 * ((size_t)E + idx)]; }
      else      { src = (int)ei[(size_t)idx];     dst = (int)ei[(size_t)E + idx]; }
      dstv[e] = dst; srcv[e] = src; av[e] = ea[idx];
      rk[e] = atomicAdd(&cnt[dst >> 9], 1);
    } else dstv[e] = -1;
  }
  __syncthreads();
  for (int b = tid; b < 1024; b += 256) {
    int c = cnt[b];
    cnt[b] = c ? atomicAdd(&bCur[b], c) : 0;  // cnt[b] becomes this block's base
  }
  __syncthreads();
#pragma unroll
  for (int e = 0; e < 8; ++e) {
    if (dstv[e] < 0) continue;
    float a = av[e];
    // p = #{sorted thresholds < a}; 6-step search saturates at 63, final step
    // admits p=64 (R4 bug, fixed R5).
    int p = 0;
#pragma unroll
    for (int s = 32; s > 0; s >>= 1) if (tss[p + s - 1] < a) p += s;
    if (tss[p] < a) ++p;
    int pos = cnt[dstv[e] >> 9] + rk[e];
    stage[pos] = make_int2(srcv[e] | (p << 20), __float_as_int(a));
    dstw[pos] = (unsigned short)(dstv[e] & 511);
  }
}

// One block per bucket (512 dst nodes): LDS histogram + scan -> final offs and
// dst-ordered pay[]. All global writes confined to the bucket's contiguous region
// (stays in one XCD's L2 -> writeback once, no partial-line amplification).
__global__ __launch_bounds__(256) void k_blocal(
    const int* __restrict__ bOffs, const int2* __restrict__ stage,
    const unsigned short* __restrict__ dstw,
    int* __restrict__ offs, int2* __restrict__ pay, int N) {
  __shared__ int h[512], cur[512], ps2[256];
  const int tid = threadIdx.x;
  const int b = blockIdx.x;
  const int s = bOffs[b], e2 = bOffs[b + 1];
  h[tid] = 0; h[tid + 256] = 0;
  __syncthreads();
  for (int j = s + tid; j < e2; j += 256) atomicAdd(&h[dstw[j]], 1);
  __syncthreads();
  int a0 = h[2 * tid], a1 = h[2 * tid + 1];
  ps2[tid] = a0 + a1;
  __syncthreads();
  for (int d = 1; d < 256; d <<= 1) {
    int add = (tid >= d) ? ps2[tid - d] : 0;
    __syncthreads();
    ps2[tid] += add;
    __syncthreads();
  }
  int ex = s + ps2[tid] - (a0 + a1);  // exclusive pair base, absolute
  cur[2 * tid] = ex;
  cur[2 * tid + 1] = ex + a0;
  {
    int nd0 = b * 512 + 2 * tid;
    if (nd0 < N) offs[nd0] = ex;
    if (nd0 + 1 < N) offs[nd0 + 1] = ex + a0;
  }
  __syncthreads();
  for (int j = s + tid; j < e2; j += 256) {
    int pos = atomicAdd(&cur[dstw[j]], 1);
    pay[pos] = stage[j];
  }
}

// ---- conv / mlp / classify ----

__global__ __launch_bounds__(256, 6) void k_conv(
    const ushort16* __restrict__ xb,
    const int* __restrict__ offs, const int2* __restrict__ pay,
    const uint32* __restrict__ ABp, const float* __restrict__ epsp,
    ushort16* __restrict__ uout, int n) {
  __shared__ uint32 ABs[65 * 64];  // packed bf16 A|B<<16: 16.6 KB
  {
    const uint4* g4 = (const uint4*)ABp;
    uint4* s4 = (uint4*)ABs;
    for (int i = threadIdx.x; i < 65 * 16; i += 256) s4[i] = g4[i];
  }
  __syncthreads();
  const uint32 lane = threadIdx.x & 63;
  const int wid = threadIdx.x >> 6;
  const float scale = 1.0f + epsp[0];
  for (int node = blockIdx.x * 4 + wid; node < n; node += gridDim.x * 4) {
    int s = offs[node], e = offs[node + 1];
    float acc = 0.0f;
    int i = s;
    if (i + 7 < e) {
      int2 qc[8];
#pragma unroll
      for (int t = 0; t < 8; ++t) qc[t] = pay[i + t];
      for (; i + 7 < e; i += 8) {
        const bool more = (i + 15 < e);   // wave-uniform (same node across lanes)
        int2 qn[8];
        if (more) {
#pragma unroll
          for (int t = 0; t < 8; ++t) qn[t] = pay[i + 8 + t];
        }
        float xv[8]; uint32 ab[8];
#pragma unroll
        for (int t = 0; t < 8; ++t) {
          uint32 so = ((uint32)qc[t].x & 0xFFFFFu) * 64u + lane;
          xv[t] = bf2f(xb[so]);
          ab[t] = ABs[((uint32)qc[t].x >> 20) * 64 + lane];
        }
#pragma unroll
        for (int t = 0; t < 8; ++t)
          acc += fmaxf(fmaf(__int_as_float(qc[t].y), __uint_as_float(ab[t] << 16),
                            __uint_as_float(ab[t] & 0xffff0000u)) + xv[t], 0.0f);
        if (more) {
#pragma unroll
          for (int t = 0; t < 8; ++t) qc[t] = qn[t];
        }
      }
    }
    for (; i < e; ++i) {
      int2 q0 = pay[i];
      uint32 so = ((uint32)q0.x & 0xFFFFFu) * 64u + lane;
      float x0 = bf2f(xb[so]);
      uint32 u0 = ABs[((uint32)q0.x >> 20) * 64 + lane];
      acc += fmaxf(fmaf(__int_as_float(q0.y), __uint_as_float(u0 << 16),
                        __uint_as_float(u0 & 0xffff0000u)) + x0, 0.0f);
    }
    float xs = bf2f(xb[(size_t)node * 64 + lane]);  // self-term from bf16 table
    uout[(size_t)node * 64 + lane] = f2bf(fmaf(scale, xs, acc));
  }
}

// Weights-in-registers node-streaming MLP. wave = one node/iter, lane = output
// feature. W1/W2 columns (W[j][lane]) live in 128 VGPRs, loaded once per wave
// via 128 coalesced dword loads. u-row staged in a 256B per-wave LDS row (f32),
// read back as broadcast float4 (all lanes same address -> conflict-free).
// 4 partial accumulators break the 64-FMA dependence chain.
__global__ __launch_bounds__(256, 2) void k_mlp(
    const ushort16* __restrict__ uin, float* __restrict__ hout,
    ushort16* __restrict__ houtb,
    const float* __restrict__ W1, const float* __restrict__ B1,
    const float* __restrict__ W2, const float* __restrict__ B2,
    int n, int wf32, int wbf16) {
  __shared__ __align__(16) float rows[4][64];
  const int lane = threadIdx.x & 63;
  const int wid = threadIdx.x >> 6;
  float W1c[64], W2c[64];
#pragma unroll
  for (int j = 0; j < 64; ++j) W1c[j] = W1[j * 64 + lane];
#pragma unroll
  for (int j = 0; j < 64; ++j) W2c[j] = W2[j * 64 + lane];
  const float b1v = B1[lane], b2v = B2[lane];
  const float4* rv = (const float4*)rows[wid];
  for (int node0 = blockIdx.x * 4; node0 < n; node0 += gridDim.x * 4) {
    const int node = node0 + wid;
    const bool active = node < n;
    if (active) rows[wid][lane] = bf2f(uin[(size_t)node * 64 + lane]);
    __syncthreads();
    float a0 = b1v, a1 = 0.0f, a2 = 0.0f, a3 = 0.0f;
#pragma unroll
    for (int c = 0; c < 16; ++c) {
      float4 uv = rv[c];
      a0 = fmaf(uv.x, W1c[4 * c + 0], a0);
      a1 = fmaf(uv.y, W1c[4 * c + 1], a1);
      a2 = fmaf(uv.z, W1c[4 * c + 2], a2);
      a3 = fmaf(uv.w, W1c[4 * c + 3], a3);
    }
    rows[wid][lane] = fmaxf((a0 + a1) + (a2 + a3), 0.0f);
    __syncthreads();
    a0 = b2v; a1 = 0.0f; a2 = 0.0f; a3 = 0.0f;
#pragma unroll
    for (int c = 0; c < 16; ++c) {
      float4 uv = rv[c];
      a0 = fmaf(uv.x, W2c[4 * c + 0], a0);
      a1 = fmaf(uv.y, W2c[4 * c + 1], a1);
      a2 = fmaf(uv.z, W2c[4 * c + 2], a2);
      a3 = fmaf(uv.w, W2c[4 * c + 3], a3);
    }
    float h2r = fmaxf((a0 + a1) + (a2 + a3), 0.0f);
    if (active) {
      if (wf32) hout[(size_t)node * 64 + lane] = h2r;
      if (wbf16) houtb[(size_t)node * 64 + lane] = f2bf(h2r);
    }
  }
}

__global__ __launch_bounds__(128) void k_classify(
    const float* __restrict__ hin, const float* __restrict__ LW,
    const float* __restrict__ LB, float* __restrict__ out, int n) {
  __shared__ float row[128 * 65];
  const int tid = threadIdx.x;
  const size_t base = (size_t)blockIdx.x * 128 * 64;
  for (int k = 0; k < 64; ++k) {
    int f = k * 128 + tid;
    row[(f >> 6) * 65 + (f & 63)] = hin[base + f];
  }
  __syncthreads();
  int node = blockIdx.x * 128 + tid;
  float lg[40];
#pragma unroll
  for (int c = 0; c < 40; ++c) lg[c] = LB[c];
  const float* r = &row[tid * 65];
  for (int j = 0; j < 64; ++j) {
    float hj = r[j];
    const float* w = &LW[j * 40];
#pragma unroll
    for (int c = 0; c < 40; ++c) lg[c] = fmaf(hj, w[c], lg[c]);
  }
  if (node < n) {
    float mx = lg[0];
#pragma unroll
    for (int c = 1; c < 40; ++c) mx = fmaxf(mx, lg[c]);
    float se = 0.0f;
#pragma unroll
    for (int c = 0; c < 40; ++c) se += __expf(lg[c] - mx);
    float lse = mx + __logf(se);
    float* o = out + (size_t)node * 40;
#pragma unroll
    for (int q = 0; q < 10; ++q) {
      float4 v = make_float4(lg[q * 4] - lse, lg[q * 4 + 1] - lse,
                             lg[q * 4 + 2] - lse, lg[q * 4 + 3] - lse);
      *(float4*)(o + q * 4) = v;
    }
  }
}

extern "C" void kernel_launch(void* const* d_in, const int* in_sizes, int n_in,
                              void* d_out, int out_size, void* d_ws, size_t ws_size,
                              hipStream_t stream) {
  (void)n_in; (void)out_size; (void)ws_size;
  const float* x     = (const float*)d_in[0];
  const uint32* ei   = (const uint32*)d_in[1];
  const float* eattr = (const float*)d_in[2];
  const float* e_w1 = (const float*)d_in[3];
  const float* e_b1 = (const float*)d_in[4];
  const float* e_w2 = (const float*)d_in[5];
  const float* e_b2 = (const float*)d_in[6];
  const float* eps1 = (const float*)d_in[7];
  const float* m1w1 = (const float*)d_in[8];
  const float* m1b1 = (const float*)d_in[9];
  const float* m1w2 = (const float*)d_in[10];
  const float* m1b2 = (const float*)d_in[11];
  const float* eps2 = (const float*)d_in[12];
  const float* m2w1 = (const float*)d_in[13];
  const float* m2b1 = (const float*)d_in[14];
  const float* m2w2 = (const float*)d_in[15];
  const float* m2b2 = (const float*)d_in[16];
  const float* linw = (const float*)d_in[17];
  const float* linb = (const float*)d_in[18];

  const int N = in_sizes[0] / 64;
  const int E = in_sizes[1] / 2;
  const int NBKT = (N + 511) >> 9;   // 512-node buckets (<=1024 for N <= 524288)

  char* ws = (char*)d_ws;
  size_t off = 0;
  auto alloc = [&](size_t bytes, size_t align) {
    off = (off + align - 1) & ~(align - 1);
    size_t r = off; off += bytes; return r;
  };
  size_t oT    = alloc(64 * 4, 64);
  size_t oAB   = alloc(65 * 64 * 4, 64);
  size_t oH1   = alloc(1024 * 4, 128);
  size_t oBO   = alloc(1025 * 4, 128);
  size_t oBC   = alloc(1024 * 4, 128);
  size_t oOffs = alloc(((size_t)N + 1) * 4, 128);
  size_t oPay  = alloc((size_t)E * 8, 256);
  size_t oXb   = alloc((size_t)N * 64 * 2 + 32768, 256);   // bf16 gather table (+tail pad)
  size_t oU    = alloc((size_t)N * 64 * 2 + 32768, 1024);  // bf16 u (+tail pad)
  size_t oH    = alloc((size_t)N * 64 * 4 + 65536, 1024);  // f32 h (+tail pad)

  float*  tsS  = (float*)(ws + oT);
  uint32* ABp  = (uint32*)(ws + oAB);
  int*    h1   = (int*)(ws + oH1);
  int*    bOffs= (int*)(ws + oBO);
  int*    bCur = (int*)(ws + oBC);
  int*    offs = (int*)(ws + oOffs);
  int2*   pay  = (int2*)(ws + oPay);
  ushort16* xb = (ushort16*)(ws + oXb);
  ushort16* ubuf = (ushort16*)(ws + oU);
  float*  hbuf = (float*)(ws + oH);
  // partition staging aliases hbuf (E*10B = 16MB <= 25.7MB); dead after k_blocal,
  // and hbuf f32 is only written by mlp2 (wf32=1) -> no conflict.
  int2*   stage = (int2*)(ws + oH);
  unsigned short* dstw = (unsigned short*)(ws + oH + (size_t)E * 8);

  hipMemsetAsync(ws + oH1, 0, 1024 * 4, stream);

  const int MB = (N + 127) / 128;
  const int CB = (N * 64 / 4 + 255) / 256;
  const int PB = (E + 2047) / 2048;

  k_setup<<<65, 256, 0, stream>>>(e_w1, e_b1, e_w2, e_b2, tsS, ABp);
  k_cast<<<CB, 256, 0, stream>>>(x, xb, N * 64 / 4);
  k_bcount<<<1024, 256, 0, stream>>>(ei, h1, E);
  k_bscan<<<1, 256, 0, stream>>>(h1, bOffs, bCur, offs, N, E);
  k_bpart<<<PB, 256, 0, stream>>>(ei, eattr, tsS, bCur, stage, dstw, E);
  k_blocal<<<NBKT, 256, 0, stream>>>(bOffs, stage, dstw, offs, pay, N);
  k_conv<<<2048, 256, 0, stream>>>(xb, offs, pay, ABp, eps1, ubuf, N);
  k_mlp<<<512, 256, 0, stream>>>(ubuf, hbuf, xb, m1w1, m1b1, m1w2, m1b2, N, 0, 1);
  k_conv<<<2048, 256, 0, stream>>>(xb, offs, pay, ABp, eps2, ubuf, N);
  k_mlp<<<512, 256, 0, stream>>>(ubuf, hbuf, xb, m2w1, m2b1, m2w2, m2b2, N, 1, 0);
  k_classify<<<MB, 128, 0, stream>>>(hbuf, linw, linb, (float*)d_out, N);
}

// Round 8
// 535.833 us; speedup vs baseline: 1.0535x; 1.0535x over previous
//
#include <hip/hip_runtime.h>
#include <hip/hip_bf16.h>
#include <stdint.h>

// GINE net, MI355X. Pipeline (R8):
//   k_setup  : piecewise-linear edge-MLP coeffs ABp[65][64] (packed bf16 A|B<<16) +
//              SORTED thresholds tsS[64] (+inf padded)
//   k_cast   : f32 -> bf16 node-feature gather table
//   CSR build (radix by dst>>9, 512-node buckets):
//     k_bcount -> k_bscan -> k_bpart (int2 stage + u16 dstl) -> k_blocal
//   k_conv   : u = bf16((1+eps)*bf16(x) + sum relu(bf16(x[src]) + a*A_p + B_p));
//              PREDICATED 8-wide gather loop (no scalar tail). R7's explicit qc/qn
//              prefetch pipeline REGRESSED 72->106us (VGPR 24->36, occ 70->46%):
//              compiler-scheduled simple form wins; don't re-add manual pipelining.
//   k_mlp    : weights-in-registers node-streaming MLP (wave=node, lane=out feat)
//   k_classify: logits + log_softmax

typedef unsigned int uint32;
typedef unsigned short ushort16;

static __device__ __forceinline__ unsigned short f2bf(float f) {
  __hip_bfloat16 h = __float2bfloat16(f);
  return *reinterpret_cast<unsigned short*>(&h);
}
static __device__ __forceinline__ float bf2f(unsigned short u) {
  return __uint_as_float(((uint32)u) << 16);
}

// One block per piece p (65 blocks). w2/b2 staged in LDS. Block 0 additionally emits
// sorted thresholds tsS (ascending; invalid units -> +inf at the tail).
__global__ __launch_bounds__(256) void k_setup(
    const float* __restrict__ w1, const float* __restrict__ b1,
    const float* __restrict__ w2, const float* __restrict__ b2,
    float* __restrict__ tsS, uint32* __restrict__ ABp) {
  __shared__ float w2s[64 * 64];
  __shared__ float b2s[64];
  __shared__ float w1s[64], b1s[64], ts[64];
  __shared__ int rs[64], ms[64], vs[64];
  const int tid = threadIdx.x;
  const int p = blockIdx.x;
  {
    const float4* g4 = (const float4*)w2;
    float4* s4 = (float4*)w2s;
    for (int i = tid; i < 64 * 16; i += 256) s4[i] = g4[i];
    if (tid < 64) b2s[tid] = b2[tid];
  }
  if (tid < 64) {
    float w = w1[tid], b = b1[tid];
    w1s[tid] = w; b1s[tid] = b;
    int v = (w != 0.0f);
    vs[tid] = v;
    ts[tid] = v ? (-b / w) : 0.0f;
  }
  __syncthreads();
  if (tid < 64) {
    float tk = ts[tid];
    int r = 0, m = 0;
    for (int k = 0; k < 64; ++k) if (vs[k]) { r += (ts[k] < tk) ? 1 : 0; m += (ts[k] == tk) ? 1 : 0; }
    rs[tid] = r; ms[tid] = m;
    if (p == 0) {
      int pos;
      if (vs[tid]) {
        int c = 0;
        for (int j = 0; j < 64; ++j)
          if (vs[j] && (ts[j] < tk || (ts[j] == tk && j < tid))) c++;
        pos = c;
      } else {
        int c = 0;
        for (int j = 0; j < 64; ++j) if (vs[j]) c++;
        for (int j = 0; j < tid; ++j) if (!vs[j]) c++;
        pos = c;
      }
      tsS[pos] = vs[tid] ? tk : __builtin_inff();
    }
  }
  __syncthreads();
  // piece p = #{thresholds < a}. Unit k active at piece p:
  //   w1>0: p >= r_k+m_k ; w1<0: p <= r_k ; w1==0: b1>0
  if (tid < 64) {
    const int j = tid;
    float accA = 0.0f, accB = b2s[j];
    for (int k = 0; k < 64; ++k) {
      bool act;
      if (vs[k]) act = (w1s[k] > 0.0f) ? (p >= rs[k] + ms[k]) : (p <= rs[k]);
      else       act = (b1s[k] > 0.0f);
      if (act) { float wv = w2s[k * 64 + j]; accA = fmaf(w1s[k], wv, accA); accB = fmaf(b1s[k], wv, accB); }
    }
    ABp[p * 64 + j] = (uint32)f2bf(accA) | ((uint32)f2bf(accB) << 16);
  }
}

__global__ void k_cast(const float* __restrict__ in, ushort16* __restrict__ out, int n4) {
  int i = blockIdx.x * blockDim.x + threadIdx.x;
  if (i >= n4) return;
  float4 v = ((const float4*)in)[i];
  ushort4 o;
  o.x = f2bf(v.x); o.y = f2bf(v.y); o.z = f2bf(v.z); o.w = f2bf(v.w);
  ((ushort4*)out)[i] = o;
}

// Inline width detection: odd 32-bit words of edge_index are int64 high-halves
// (all zero, idx < 2^20) or int32 src values (~never 64 consecutive zeros).
static __device__ __forceinline__ bool detect_is64(const uint32* ei, int E, int tid, int* sflag) {
  if (tid < 64) {
    int lim = (E < 64) ? E : 64;
    int nz = (tid < lim) ? (ei[2 * (size_t)tid + 1] != 0u) : 0;
    nz = __any(nz);
    if (tid == 0) *sflag = !nz;
  }
  __syncthreads();
  return *sflag != 0;
}

// ---- CSR build: radix partition by dst>>9 (512-node buckets) ----

__global__ __launch_bounds__(256) void k_bcount(
    const uint32* __restrict__ ei, int* __restrict__ hist1, int E) {
  __shared__ int h[1024];
  __shared__ int sIs64;
  for (int i = threadIdx.x; i < 1024; i += 256) h[i] = 0;
  bool is64 = detect_is64(ei, E, threadIdx.x, &sIs64);  // has __syncthreads
  for (int i = blockIdx.x * blockDim.x + threadIdx.x; i < E; i += gridDim.x * blockDim.x) {
    int dst = is64 ? (int)ei[2 * ((size_t)E + i)] : (int)ei[(size_t)E + i];
    atomicAdd(&h[dst >> 9], 1);
  }
  __syncthreads();
  for (int i = threadIdx.x; i < 1024; i += 256)
    if (h[i]) atomicAdd(&hist1[i], h[i]);
}

__global__ __launch_bounds__(256) void k_bscan(
    const int* __restrict__ hist1, int* __restrict__ bOffs, int* __restrict__ bCur,
    int* __restrict__ offs, int N, int E) {
  __shared__ int psum[256];
  const int tid = threadIdx.x;
  int v0 = hist1[tid * 4 + 0], v1 = hist1[tid * 4 + 1];
  int v2 = hist1[tid * 4 + 2], v3 = hist1[tid * 4 + 3];
  int sum = v0 + v1 + v2 + v3;
  psum[tid] = sum;
  __syncthreads();
  for (int d = 1; d < 256; d <<= 1) {
    int add = (tid >= d) ? psum[tid - d] : 0;
    __syncthreads();
    psum[tid] += add;
    __syncthreads();
  }
  int run = psum[tid] - sum;  // exclusive
  bOffs[tid * 4 + 0] = run; bCur[tid * 4 + 0] = run; run += v0;
  bOffs[tid * 4 + 1] = run; bCur[tid * 4 + 1] = run; run += v1;
  bOffs[tid * 4 + 2] = run; bCur[tid * 4 + 2] = run; run += v2;
  bOffs[tid * 4 + 3] = run; bCur[tid * 4 + 3] = run; run += v3;
  if (tid == 255) bOffs[1024] = run;  // == E
  if (tid == 0) offs[N] = E;
}

// tile = 2048 edges/block, 8 per thread. Ranks via LDS atomics; one global atomic
// per (block, nonempty bucket). 512-node buckets -> ~10-edge contiguous runs.
__global__ __launch_bounds__(256) void k_bpart(
    const uint32* __restrict__ ei, const float* __restrict__ ea,
    const float* __restrict__ tsSg, int* __restrict__ bCur,
    int2* __restrict__ stage, unsigned short* __restrict__ dstw, int E) {
  __shared__ int cnt[1024];
  __shared__ float tss[64];
  __shared__ int sIs64;
  const int tid = threadIdx.x;
  for (int i = tid; i < 1024; i += 256) cnt[i] = 0;
  if (tid >= 64 && tid < 128) tss[tid - 64] = tsSg[tid - 64];
  bool is64 = detect_is64(ei, E, tid, &sIs64);  // has __syncthreads
  const int base0 = blockIdx.x * 2048;
  int dstv[8], srcv[8], rk[8];
  float av[8];
#pragma unroll
  for (int e = 0; e < 8; ++e) {
    int idx = base0 + e * 256 + tid;
    if (idx < E) {
      int src, dst;
      if (is64) { src = (int)ei[2 * (size_t)idx]; dst = (int)ei[2 * ((size_t)E + idx)]; }
      else      { src = (int)ei[(size_t)idx];     dst = (int)ei[(size_t)E + idx]; }
      dstv[e] = dst; srcv[e] = src; av[e] = ea[idx];
      rk[e] = atomicAdd(&cnt[dst >> 9], 1);
    } else dstv[e] = -1;
  }
  __syncthreads();
  for (int b = tid; b < 1024; b += 256) {
    int c = cnt[b];
    cnt[b] = c ? atomicAdd(&bCur[b], c) : 0;  // cnt[b] becomes this block's base
  }
  __syncthreads();
#pragma unroll
  for (int e = 0; e < 8; ++e) {
    if (dstv[e] < 0) continue;
    float a = av[e];
    // p = #{sorted thresholds < a}; 6-step search saturates at 63, final step
    // admits p=64 (R4 bug, fixed R5).
    int p = 0;
#pragma unroll
    for (int s = 32; s > 0; s >>= 1) if (tss[p + s - 1] < a) p += s;
    if (tss[p] < a) ++p;
    int pos = cnt[dstv[e] >> 9] + rk[e];
    stage[pos] = make_int2(srcv[e] | (p << 20), __float_as_int(a));
    dstw[pos] = (unsigned short)(dstv[e] & 511);
  }
}

// One block per bucket (512 dst nodes): LDS histogram + scan -> final offs and
// dst-ordered pay[]. All global writes confined to the bucket's contiguous region.
__global__ __launch_bounds__(256) void k_blocal(
    const int* __restrict__ bOffs, const int2* __restrict__ stage,
    const unsigned short* __restrict__ dstw,
    int* __restrict__ offs, int2* __restrict__ pay, int N) {
  __shared__ int h[512], cur[512], ps2[256];
  const int tid = threadIdx.x;
  const int b = blockIdx.x;
  const int s = bOffs[b], e2 = bOffs[b + 1];
  h[tid] = 0; h[tid + 256] = 0;
  __syncthreads();
  for (int j = s + tid; j < e2; j += 256) atomicAdd(&h[dstw[j]], 1);
  __syncthreads();
  int a0 = h[2 * tid], a1 = h[2 * tid + 1];
  ps2[tid] = a0 + a1;
  __syncthreads();
  for (int d = 1; d < 256; d <<= 1) {
    int add = (tid >= d) ? ps2[tid - d] : 0;
    __syncthreads();
    ps2[tid] += add;
    __syncthreads();
  }
  int ex = s + ps2[tid] - (a0 + a1);  // exclusive pair base, absolute
  cur[2 * tid] = ex;
  cur[2 * tid + 1] = ex + a0;
  {
    int nd0 = b * 512 + 2 * tid;
    if (nd0 < N) offs[nd0] = ex;
    if (nd0 + 1 < N) offs[nd0 + 1] = ex + a0;
  }
  __syncthreads();
  for (int j = s + tid; j < e2; j += 256) {
    int pos = atomicAdd(&cur[dstw[j]], 1);
    pay[pos] = stage[j];
  }
}

// ---- conv / mlp / classify ----

// Predicated 8-wide gather loop: every iteration keeps 8 gathers in flight, tail
// lanes clamp to edge e-1 (same line, L2-hot) and mask their contribution.
__global__ __launch_bounds__(256) void k_conv(
    const ushort16* __restrict__ xb,
    const int* __restrict__ offs, const int2* __restrict__ pay,
    const uint32* __restrict__ ABp, const float* __restrict__ epsp,
    ushort16* __restrict__ uout, int n) {
  __shared__ uint32 ABs[65 * 64];  // packed bf16 A|B<<16: 16.6 KB
  {
    const uint4* g4 = (const uint4*)ABp;
    uint4* s4 = (uint4*)ABs;
    for (int i = threadIdx.x; i < 65 * 16; i += 256) s4[i] = g4[i];
  }
  __syncthreads();
  const uint32 lane = threadIdx.x & 63;
  const int wid = threadIdx.x >> 6;
  const float scale = 1.0f + epsp[0];
  for (int node = blockIdx.x * 4 + wid; node < n; node += gridDim.x * 4) {
    const int s = offs[node], e = offs[node + 1];
    float acc = 0.0f;
    for (int i = s; i < e; i += 8) {
      int2 q[8];
#pragma unroll
      for (int t = 0; t < 8; ++t) {
        int idx = i + t;
        idx = (idx < e) ? idx : (e - 1);   // clamp: loop body implies e > s
        q[t] = pay[idx];
      }
      float xv[8]; uint32 ab[8];
#pragma unroll
      for (int t = 0; t < 8; ++t) {
        uint32 so = ((uint32)q[t].x & 0xFFFFFu) * 64u + lane;
        xv[t] = bf2f(xb[so]);
        ab[t] = ABs[((uint32)q[t].x >> 20) * 64 + lane];
      }
#pragma unroll
      for (int t = 0; t < 8; ++t) {
        float val = fmaxf(fmaf(__int_as_float(q[t].y), __uint_as_float(ab[t] << 16),
                               __uint_as_float(ab[t] & 0xffff0000u)) + xv[t], 0.0f);
        acc += (i + t < e) ? val : 0.0f;
      }
    }
    float xs = bf2f(xb[(size_t)node * 64 + lane]);  // self-term from bf16 table
    uout[(size_t)node * 64 + lane] = f2bf(fmaf(scale, xs, acc));
  }
}

// Weights-in-registers node-streaming MLP. wave = one node/iter, lane = output
// feature. W1/W2 columns in 128 VGPRs (coalesced 256B loads, once per wave).
// u-row staged in per-wave LDS row, read back as broadcast float4.
__global__ __launch_bounds__(256, 2) void k_mlp(
    const ushort16* __restrict__ uin, float* __restrict__ hout,
    ushort16* __restrict__ houtb,
    const float* __restrict__ W1, const float* __restrict__ B1,
    const float* __restrict__ W2, const float* __restrict__ B2,
    int n, int wf32, int wbf16) {
  __shared__ __align__(16) float rows[4][64];
  const int lane = threadIdx.x & 63;
  const int wid = threadIdx.x >> 6;
  float W1c[64], W2c[64];
#pragma unroll
  for (int j = 0; j < 64; ++j) W1c[j] = W1[j * 64 + lane];
#pragma unroll
  for (int j = 0; j < 64; ++j) W2c[j] = W2[j * 64 + lane];
  const float b1v = B1[lane], b2v = B2[lane];
  const float4* rv = (const float4*)rows[wid];
  for (int node0 = blockIdx.x * 4; node0 < n; node0 += gridDim.x * 4) {
    const int node = node0 + wid;
    const bool active = node < n;
    if (active) rows[wid][lane] = bf2f(uin[(size_t)node * 64 + lane]);
    __syncthreads();
    float a0 = b1v, a1 = 0.0f, a2 = 0.0f, a3 = 0.0f;
#pragma unroll
    for (int c = 0; c < 16; ++c) {
      float4 uv = rv[c];
      a0 = fmaf(uv.x, W1c[4 * c + 0], a0);
      a1 = fmaf(uv.y, W1c[4 * c + 1], a1);
      a2 = fmaf(uv.z, W1c[4 * c + 2], a2);
      a3 = fmaf(uv.w, W1c[4 * c + 3], a3);
    }
    rows[wid][lane] = fmaxf((a0 + a1) + (a2 + a3), 0.0f);
    __syncthreads();
    a0 = b2v; a1 = 0.0f; a2 = 0.0f; a3 = 0.0f;
#pragma unroll
    for (int c = 0; c < 16; ++c) {
      float4 uv = rv[c];
      a0 = fmaf(uv.x, W2c[4 * c + 0], a0);
      a1 = fmaf(uv.y, W2c[4 * c + 1], a1);
      a2 = fmaf(uv.z, W2c[4 * c + 2], a2);
      a3 = fmaf(uv.w, W2c[4 * c + 3], a3);
    }
    float h2r = fmaxf((a0 + a1) + (a2 + a3), 0.0f);
    if (active) {
      if (wf32) hout[(size_t)node * 64 + lane] = h2r;
      if (wbf16) houtb[(size_t)node * 64 + lane] = f2bf(h2r);
    }
  }
}

__global__ __launch_bounds__(128) void k_classify(
    const float* __restrict__ hin, const float* __restrict__ LW,
    const float* __restrict__ LB, float* __restrict__ out, int n) {
  __shared__ float row[128 * 65];
  const int tid = threadIdx.x;
  const size_t base = (size_t)blockIdx.x * 128 * 64;
  for (int k = 0; k < 64; ++k) {
    int f = k * 128 + tid;
    row[(f >> 6) * 65 + (f & 63)] = hin[base + f];
  }
  __syncthreads();
  int node = blockIdx.x * 128 + tid;
  float lg[40];
#pragma unroll
  for (int c = 0; c < 40; ++c) lg[c] = LB[c];
  const float* r = &row[tid * 65];
  for (int j = 0; j < 64; ++j) {
    float hj = r[j];
    const float* w = &LW[j * 40];
#pragma unroll
    for (int c = 0; c < 40; ++c) lg[c] = fmaf(hj, w[c], lg[c]);
  }
  if (node < n) {
    float mx = lg[0];
#pragma unroll
    for (int c = 1; c < 40; ++c) mx = fmaxf(mx, lg[c]);
    float se = 0.0f;
#pragma unroll
    for (int c = 0; c < 40; ++c) se += __expf(lg[c] - mx);
    float lse = mx + __logf(se);
    float* o = out + (size_t)node * 40;
#pragma unroll
    for (int q = 0; q < 10; ++q) {
      float4 v = make_float4(lg[q * 4] - lse, lg[q * 4 + 1] - lse,
                             lg[q * 4 + 2] - lse, lg[q * 4 + 3] - lse);
      *(float4*)(o + q * 4) = v;
    }
  }
}

extern "C" void kernel_launch(void* const* d_in, const int* in_sizes, int n_in,
                              void* d_out, int out_size, void* d_ws, size_t ws_size,
                              hipStream_t stream) {
  (void)n_in; (void)out_size; (void)ws_size;
  const float* x     = (const float*)d_in[0];
  const uint32* ei   = (const uint32*)d_in[1];
  const float* eattr = (const float*)d_in[2];
  const float* e_w1 = (const float*)d_in[3];
  const float* e_b1 = (const float*)d_in[4];
  const float* e_w2 = (const float*)d_in[5];
  const float* e_b2 = (const float*)d_in[6];
  const float* eps1 = (const float*)d_in[7];
  const float* m1w1 = (const float*)d_in[8];
  const float* m1b1 = (const float*)d_in[9];
  const float* m1w2 = (const float*)d_in[10];
  const float* m1b2 = (const float*)d_in[11];
  const float* eps2 = (const float*)d_in[12];
  const float* m2w1 = (const float*)d_in[13];
  const float* m2b1 = (const float*)d_in[14];
  const float* m2w2 = (const float*)d_in[15];
  const float* m2b2 = (const float*)d_in[16];
  const float* linw = (const float*)d_in[17];
  const float* linb = (const float*)d_in[18];

  const int N = in_sizes[0] / 64;
  const int E = in_sizes[1] / 2;
  const int NBKT = (N + 511) >> 9;   // 512-node buckets

  char* ws = (char*)d_ws;
  size_t off = 0;
  auto alloc = [&](size_t bytes, size_t align) {
    off = (off + align - 1) & ~(align - 1);
    size_t r = off; off += bytes; return r;
  };
  size_t oT    = alloc(64 * 4, 64);
  size_t oAB   = alloc(65 * 64 * 4, 64);
  size_t oH1   = alloc(1024 * 4, 128);
  size_t oBO   = alloc(1025 * 4, 128);
  size_t oBC   = alloc(1024 * 4, 128);
  size_t oOffs = alloc(((size_t)N + 1) * 4, 128);
  size_t oPay  = alloc((size_t)E * 8, 256);
  size_t oXb   = alloc((size_t)N * 64 * 2 + 32768, 256);   // bf16 gather table (+tail pad)
  size_t oU    = alloc((size_t)N * 64 * 2 + 32768, 1024);  // bf16 u (+tail pad)
  size_t oH    = alloc((size_t)N * 64 * 4 + 65536, 1024);  // f32 h (+tail pad)

  float*  tsS  = (float*)(ws + oT);
  uint32* ABp  = (uint32*)(ws + oAB);
  int*    h1   = (int*)(ws + oH1);
  int*    bOffs= (int*)(ws + oBO);
  int*    bCur = (int*)(ws + oBC);
  int*    offs = (int*)(ws + oOffs);
  int2*   pay  = (int2*)(ws + oPay);
  ushort16* xb = (ushort16*)(ws + oXb);
  ushort16* ubuf = (ushort16*)(ws + oU);
  float*  hbuf = (float*)(ws + oH);
  // partition staging aliases hbuf (E*10B = 16MB <= 25.7MB); dead after k_blocal,
  // and hbuf f32 is only written by mlp2 (wf32=1) -> no conflict.
  int2*   stage = (int2*)(ws + oH);
  unsigned short* dstw = (unsigned short*)(ws + oH + (size_t)E * 8);

  hipMemsetAsync(ws + oH1, 0, 1024 * 4, stream);

  const int MB = (N + 127) / 128;
  const int CB = (N * 64 / 4 + 255) / 256;
  const int PB = (E + 2047) / 2048;

  k_setup<<<65, 256, 0, stream>>>(e_w1, e_b1, e_w2, e_b2, tsS, ABp);
  k_cast<<<CB, 256, 0, stream>>>(x, xb, N * 64 / 4);
  k_bcount<<<1024, 256, 0, stream>>>(ei, h1, E);
  k_bscan<<<1, 256, 0, stream>>>(h1, bOffs, bCur, offs, N, E);
  k_bpart<<<PB, 256, 0, stream>>>(ei, eattr, tsS, bCur, stage, dstw, E);
  k_blocal<<<NBKT, 256, 0, stream>>>(bOffs, stage, dstw, offs, pay, N);
  k_conv<<<2048, 256, 0, stream>>>(xb, offs, pay, ABp, eps1, ubuf, N);
  k_mlp<<<512, 256, 0, stream>>>(ubuf, hbuf, xb, m1w1, m1b1, m1w2, m1b2, N, 0, 1);
  k_conv<<<2048, 256, 0, stream>>>(xb, offs, pay, ABp, eps2, ubuf, N);
  k_mlp<<<512, 256, 0, stream>>>(ubuf, hbuf, xb, m2w1, m2b1, m2w2, m2b2, N, 1, 0);
  k_classify<<<MB, 128, 0, stream>>>(hbuf, linw, linb, (float*)d_out, N);
}

// Round 9
// 487.987 us; speedup vs baseline: 1.1568x; 1.0980x over previous
//
#include <hip/hip_runtime.h>
#include <hip/hip_bf16.h>
#include <stdint.h>

// GINE net, MI355X. Pipeline (R9, 8 dispatches + 1 memset):
//   k_setup_cast : blocks 0..64 = piecewise-linear edge-MLP coeffs ABp[65][64]
//                  (packed bf16 A|B<<16) + sorted thresholds; blocks 65.. = f32->bf16 cast
//   k_bcount     : bucket histogram (dst>>9, 512-node buckets), LDS-aggregated
//   k_bpart      : in-LDS scan of hist + partition to bucket segments (stage,dstw)
//   k_blocal     : in-LDS scan + per-bucket counting sort -> offs[], pay[]
//   k_conv  x2   : u = bf16((1+eps)*bf16(x) + sum relu(bf16(x[src]) + a*A_p + B_p))
//                  R6-proven inner loop: plain 8-wide + scalar tail. R7's manual
//                  prefetch (106us) and R8's predicated loop (97us) both LOST to
//                  this compiler-scheduled form (72us) -- do not re-add.
//   k_mlp        : weights-in-regs node-streaming MLP, bf16 out only (conv2 table)
//   k_mlp_cls    : mlp2 + fused classifier + log_softmax (h never hits memory)

typedef unsigned int uint32;
typedef unsigned short ushort16;

static __device__ __forceinline__ unsigned short f2bf(float f) {
  __hip_bfloat16 h = __float2bfloat16(f);
  return *reinterpret_cast<unsigned short*>(&h);
}
static __device__ __forceinline__ float bf2f(unsigned short u) {
  return __uint_as_float(((uint32)u) << 16);
}

// ---- setup (blocks 0..64) + cast (blocks 65..) ----
__global__ __launch_bounds__(256) void k_setup_cast(
    const float* __restrict__ w1, const float* __restrict__ b1,
    const float* __restrict__ w2, const float* __restrict__ b2,
    float* __restrict__ tsS, uint32* __restrict__ ABp,
    const float* __restrict__ xin, ushort16* __restrict__ xb, int n4) {
  const int tid = threadIdx.x;
  if (blockIdx.x >= 65) {  // cast part
    int i = (blockIdx.x - 65) * 256 + tid;
    if (i < n4) {
      float4 v = ((const float4*)xin)[i];
      ushort4 o;
      o.x = f2bf(v.x); o.y = f2bf(v.y); o.z = f2bf(v.z); o.w = f2bf(v.w);
      ((ushort4*)xb)[i] = o;
    }
    return;
  }
  __shared__ float w2s[64 * 64];
  __shared__ float b2s[64];
  __shared__ float w1s[64], b1s[64], ts[64];
  __shared__ int rs[64], ms[64], vs[64];
  const int p = blockIdx.x;
  {
    const float4* g4 = (const float4*)w2;
    float4* s4 = (float4*)w2s;
    for (int i = tid; i < 64 * 16; i += 256) s4[i] = g4[i];
    if (tid < 64) b2s[tid] = b2[tid];
  }
  if (tid < 64) {
    float w = w1[tid], b = b1[tid];
    w1s[tid] = w; b1s[tid] = b;
    int v = (w != 0.0f);
    vs[tid] = v;
    ts[tid] = v ? (-b / w) : 0.0f;
  }
  __syncthreads();
  if (tid < 64) {
    float tk = ts[tid];
    int r = 0, m = 0;
    for (int k = 0; k < 64; ++k) if (vs[k]) { r += (ts[k] < tk) ? 1 : 0; m += (ts[k] == tk) ? 1 : 0; }
    rs[tid] = r; ms[tid] = m;
    if (p == 0) {
      int pos;
      if (vs[tid]) {
        int c = 0;
        for (int j = 0; j < 64; ++j)
          if (vs[j] && (ts[j] < tk || (ts[j] == tk && j < tid))) c++;
        pos = c;
      } else {
        int c = 0;
        for (int j = 0; j < 64; ++j) if (vs[j]) c++;
        for (int j = 0; j < tid; ++j) if (!vs[j]) c++;
        pos = c;
      }
      tsS[pos] = vs[tid] ? tk : __builtin_inff();
    }
  }
  __syncthreads();
  // piece p = #{thresholds < a}. Unit k active at piece p:
  //   w1>0: p >= r_k+m_k ; w1<0: p <= r_k ; w1==0: b1>0
  if (tid < 64) {
    const int j = tid;
    float accA = 0.0f, accB = b2s[j];
    for (int k = 0; k < 64; ++k) {
      bool act;
      if (vs[k]) act = (w1s[k] > 0.0f) ? (p >= rs[k] + ms[k]) : (p <= rs[k]);
      else       act = (b1s[k] > 0.0f);
      if (act) { float wv = w2s[k * 64 + j]; accA = fmaf(w1s[k], wv, accA); accB = fmaf(b1s[k], wv, accB); }
    }
    ABp[p * 64 + j] = (uint32)f2bf(accA) | ((uint32)f2bf(accB) << 16);
  }
}

// Inline width detection: odd 32-bit words of edge_index are int64 high-halves
// (all zero, idx < 2^20) or int32 src values (~never 64 consecutive zeros).
static __device__ __forceinline__ bool detect_is64(const uint32* ei, int E, int tid, int* sflag) {
  if (tid < 64) {
    int lim = (E < 64) ? E : 64;
    int nz = (tid < lim) ? (ei[2 * (size_t)tid + 1] != 0u) : 0;
    nz = __any(nz);
    if (tid == 0) *sflag = !nz;
  }
  __syncthreads();
  return *sflag != 0;
}

// In-LDS exclusive scan of hist1[1024] -> bo[1024]; returns total via bo_total.
// Call with all 256 threads; leaves result in bo; __syncthreads at end.
static __device__ __forceinline__ int scan_hist(const int* __restrict__ hist1,
                                                int* bo, int* psum, int tid) {
  int v0 = hist1[tid * 4 + 0], v1 = hist1[tid * 4 + 1];
  int v2 = hist1[tid * 4 + 2], v3 = hist1[tid * 4 + 3];
  int sum = v0 + v1 + v2 + v3;
  psum[tid] = sum;
  __syncthreads();
  for (int d = 1; d < 256; d <<= 1) {
    int add = (tid >= d) ? psum[tid - d] : 0;
    __syncthreads();
    psum[tid] += add;
    __syncthreads();
  }
  int run = psum[tid] - sum;
  bo[tid * 4 + 0] = run; run += v0;
  bo[tid * 4 + 1] = run; run += v1;
  bo[tid * 4 + 2] = run; run += v2;
  bo[tid * 4 + 3] = run; run += v3;
  int total = psum[255];
  __syncthreads();
  return total;
}

// ---- CSR build: radix partition by dst>>9 (512-node buckets) ----

__global__ __launch_bounds__(256) void k_bcount(
    const uint32* __restrict__ ei, int* __restrict__ hist1, int E) {
  __shared__ int h[1024];
  __shared__ int sIs64;
  for (int i = threadIdx.x; i < 1024; i += 256) h[i] = 0;
  bool is64 = detect_is64(ei, E, threadIdx.x, &sIs64);  // has __syncthreads
  for (int i = blockIdx.x * blockDim.x + threadIdx.x; i < E; i += gridDim.x * blockDim.x) {
    int dst = is64 ? (int)ei[2 * ((size_t)E + i)] : (int)ei[(size_t)E + i];
    atomicAdd(&h[dst >> 9], 1);
  }
  __syncthreads();
  for (int i = threadIdx.x; i < 1024; i += 256)
    if (h[i]) atomicAdd(&hist1[i], h[i]);
}

// tile = 2048 edges/block, 8 per thread. In-LDS scan gives bucket bases; ranks via
// LDS atomics; ONE global atomic per (block, nonempty bucket) on zero-init bCur.
__global__ __launch_bounds__(256) void k_bpart(
    const uint32* __restrict__ ei, const float* __restrict__ ea,
    const float* __restrict__ tsSg, const int* __restrict__ hist1,
    int* __restrict__ bCur,
    int2* __restrict__ stage, unsigned short* __restrict__ dstw, int E) {
  __shared__ int cnt[1024];
  __shared__ int bo[1024];
  __shared__ int psum[256];
  __shared__ float tss[64];
  __shared__ int sIs64;
  const int tid = threadIdx.x;
  for (int i = tid; i < 1024; i += 256) cnt[i] = 0;
  if (tid >= 64 && tid < 128) tss[tid - 64] = tsSg[tid - 64];
  bool is64 = detect_is64(ei, E, tid, &sIs64);  // has __syncthreads
  scan_hist(hist1, bo, psum, tid);
  const int base0 = blockIdx.x * 2048;
  int dstv[8], srcv[8], rk[8];
  float av[8];
#pragma unroll
  for (int e = 0; e < 8; ++e) {
    int idx = base0 + e * 256 + tid;
    if (idx < E) {
      int src, dst;
      if (is64) { src = (int)ei[2 * (size_t)idx]; dst = (int)ei[2 * ((size_t)E + idx)]; }
      else      { src = (int)ei[(size_t)idx];     dst = (int)ei[(size_t)E + idx]; }
      dstv[e] = dst; srcv[e] = src; av[e] = ea[idx];
      rk[e] = atomicAdd(&cnt[dst >> 9], 1);
    } else dstv[e] = -1;
  }
  __syncthreads();
  for (int b = tid; b < 1024; b += 256) {
    int c = cnt[b];
    cnt[b] = c ? (bo[b] + atomicAdd(&bCur[b], c)) : 0;  // block's base in bucket seg
  }
  __syncthreads();
#pragma unroll
  for (int e = 0; e < 8; ++e) {
    if (dstv[e] < 0) continue;
    float a = av[e];
    // p = #{sorted thresholds < a}; 6-step search saturates at 63, final step
    // admits p=64 (R4 bug, fixed R5).
    int p = 0;
#pragma unroll
    for (int s = 32; s > 0; s >>= 1) if (tss[p + s - 1] < a) p += s;
    if (tss[p] < a) ++p;
    int pos = cnt[dstv[e] >> 9] + rk[e];
    stage[pos] = make_int2(srcv[e] | (p << 20), __float_as_int(a));
    dstw[pos] = (unsigned short)(dstv[e] & 511);
  }
}

// One block per bucket (512 dst nodes): in-LDS scan for segment bounds, then
// LDS histogram + scan -> final offs and dst-ordered pay[].
__global__ __launch_bounds__(256) void k_blocal(
    const int* __restrict__ hist1, const int2* __restrict__ stage,
    const unsigned short* __restrict__ dstw,
    int* __restrict__ offs, int2* __restrict__ pay, int N) {
  __shared__ int bo[1024];
  __shared__ int psum[256];
  __shared__ int h[512], cur[512], ps2[256];
  const int tid = threadIdx.x;
  const int b = blockIdx.x;
  int Etot = scan_hist(hist1, bo, psum, tid);
  const int s = bo[b];
  const int e2 = (b == 1023) ? Etot : bo[b + 1];
  if (b == 0 && tid == 0) offs[N] = Etot;
  h[tid] = 0; h[tid + 256] = 0;
  __syncthreads();
  for (int j = s + tid; j < e2; j += 256) atomicAdd(&h[dstw[j]], 1);
  __syncthreads();
  int a0 = h[2 * tid], a1 = h[2 * tid + 1];
  ps2[tid] = a0 + a1;
  __syncthreads();
  for (int d = 1; d < 256; d <<= 1) {
    int add = (tid >= d) ? ps2[tid - d] : 0;
    __syncthreads();
    ps2[tid] += add;
    __syncthreads();
  }
  int ex = s + ps2[tid] - (a0 + a1);  // exclusive pair base, absolute
  cur[2 * tid] = ex;
  cur[2 * tid + 1] = ex + a0;
  {
    int nd0 = b * 512 + 2 * tid;
    if (nd0 < N) offs[nd0] = ex;
    if (nd0 + 1 < N) offs[nd0 + 1] = ex + a0;
  }
  __syncthreads();
  for (int j = s + tid; j < e2; j += 256) {
    int pos = atomicAdd(&cur[dstw[j]], 1);
    pay[pos] = stage[j];
  }
}

// ---- conv / mlp / mlp+classify ----

// R6-proven form: plain 8-wide main loop + scalar tail, compiler-scheduled.
__global__ __launch_bounds__(256) void k_conv(
    const ushort16* __restrict__ xb,
    const int* __restrict__ offs, const int2* __restrict__ pay,
    const uint32* __restrict__ ABp, const float* __restrict__ epsp,
    ushort16* __restrict__ uout, int n) {
  __shared__ uint32 ABs[65 * 64];  // packed bf16 A|B<<16: 16.6 KB
  {
    const uint4* g4 = (const uint4*)ABp;
    uint4* s4 = (uint4*)ABs;
    for (int i = threadIdx.x; i < 65 * 16; i += 256) s4[i] = g4[i];
  }
  __syncthreads();
  const uint32 lane = threadIdx.x & 63;
  const int wid = threadIdx.x >> 6;
  const float scale = 1.0f + epsp[0];
  for (int node = blockIdx.x * 4 + wid; node < n; node += gridDim.x * 4) {
    int s = offs[node], e = offs[node + 1];
    float acc = 0.0f;
    int i = s;
    for (; i + 7 < e; i += 8) {  // 8 gathers in flight
      int2 q[8]; float xv[8]; uint32 ab[8];
#pragma unroll
      for (int t = 0; t < 8; ++t) q[t] = pay[i + t];
#pragma unroll
      for (int t = 0; t < 8; ++t) {
        uint32 so = ((uint32)q[t].x & 0xFFFFFu) * 64u + lane;
        xv[t] = bf2f(xb[so]);
        ab[t] = ABs[((uint32)q[t].x >> 20) * 64 + lane];
      }
#pragma unroll
      for (int t = 0; t < 8; ++t)
        acc += fmaxf(fmaf(__int_as_float(q[t].y), __uint_as_float(ab[t] << 16),
                          __uint_as_float(ab[t] & 0xffff0000u)) + xv[t], 0.0f);
    }
    for (; i < e; ++i) {
      int2 q0 = pay[i];
      uint32 so = ((uint32)q0.x & 0xFFFFFu) * 64u + lane;
      float x0 = bf2f(xb[so]);
      uint32 u0 = ABs[((uint32)q0.x >> 20) * 64 + lane];
      acc += fmaxf(fmaf(__int_as_float(q0.y), __uint_as_float(u0 << 16),
                        __uint_as_float(u0 & 0xffff0000u)) + x0, 0.0f);
    }
    float xs = bf2f(xb[(size_t)node * 64 + lane]);  // self-term from bf16 table
    uout[(size_t)node * 64 + lane] = f2bf(fmaf(scale, xs, acc));
  }
}

// Weights-in-registers node-streaming MLP. wave = one node/iter, lane = out feature.
// rows[wid] is wave-private -> no __syncthreads needed (wave-synchronous LDS).
__global__ __launch_bounds__(256, 2) void k_mlp(
    const ushort16* __restrict__ uin, ushort16* __restrict__ houtb,
    const float* __restrict__ W1, const float* __restrict__ B1,
    const float* __restrict__ W2, const float* __restrict__ B2, int n) {
  __shared__ __align__(16) float rows[4][64];
  const int lane = threadIdx.x & 63;
  const int wid = threadIdx.x >> 6;
  float W1c[64], W2c[64];
#pragma unroll
  for (int j = 0; j < 64; ++j) W1c[j] = W1[j * 64 + lane];
#pragma unroll
  for (int j = 0; j < 64; ++j) W2c[j] = W2[j * 64 + lane];
  const float b1v = B1[lane], b2v = B2[lane];
  const float4* rv = (const float4*)rows[wid];
  for (int node = blockIdx.x * 4 + wid; node < n; node += gridDim.x * 4) {
    rows[wid][lane] = bf2f(uin[(size_t)node * 64 + lane]);
    float a0 = b1v, a1 = 0.0f, a2 = 0.0f, a3 = 0.0f;
#pragma unroll
    for (int c = 0; c < 16; ++c) {
      float4 uv = rv[c];
      a0 = fmaf(uv.x, W1c[4 * c + 0], a0);
      a1 = fmaf(uv.y, W1c[4 * c + 1], a1);
      a2 = fmaf(uv.z, W1c[4 * c + 2], a2);
      a3 = fmaf(uv.w, W1c[4 * c + 3], a3);
    }
    rows[wid][lane] = fmaxf((a0 + a1) + (a2 + a3), 0.0f);
    a0 = b2v; a1 = 0.0f; a2 = 0.0f; a3 = 0.0f;
#pragma unroll
    for (int c = 0; c < 16; ++c) {
      float4 uv = rv[c];
      a0 = fmaf(uv.x, W2c[4 * c + 0], a0);
      a1 = fmaf(uv.y, W2c[4 * c + 1], a1);
      a2 = fmaf(uv.z, W2c[4 * c + 2], a2);
      a3 = fmaf(uv.w, W2c[4 * c + 3], a3);
    }
    houtb[(size_t)node * 64 + lane] = f2bf(fmaxf((a0 + a1) + (a2 + a3), 0.0f));
  }
}

// mlp2 + fused classifier + log_softmax: h never touches global memory.
__global__ __launch_bounds__(256, 2) void k_mlp_cls(
    const ushort16* __restrict__ uin,
    const float* __restrict__ W1, const float* __restrict__ B1,
    const float* __restrict__ W2, const float* __restrict__ B2,
    const float* __restrict__ LW, const float* __restrict__ LB,
    float* __restrict__ out, int n) {
  __shared__ __align__(16) float rows[4][64];
  const int lane = threadIdx.x & 63;
  const int wid = threadIdx.x >> 6;
  float W1c[64], W2c[64], LWc[64];
#pragma unroll
  for (int j = 0; j < 64; ++j) W1c[j] = W1[j * 64 + lane];
#pragma unroll
  for (int j = 0; j < 64; ++j) W2c[j] = W2[j * 64 + lane];
  const bool cl = lane < 40;
#pragma unroll
  for (int j = 0; j < 64; ++j) LWc[j] = cl ? LW[j * 40 + lane] : 0.0f;
  const float b1v = B1[lane], b2v = B2[lane];
  const float lbv = cl ? LB[lane] : 0.0f;
  const float4* rv = (const float4*)rows[wid];
  for (int node = blockIdx.x * 4 + wid; node < n; node += gridDim.x * 4) {
    rows[wid][lane] = bf2f(uin[(size_t)node * 64 + lane]);
    float a0 = b1v, a1 = 0.0f, a2 = 0.0f, a3 = 0.0f;
#pragma unroll
    for (int c = 0; c < 16; ++c) {
      float4 uv = rv[c];
      a0 = fmaf(uv.x, W1c[4 * c + 0], a0);
      a1 = fmaf(uv.y, W1c[4 * c + 1], a1);
      a2 = fmaf(uv.z, W1c[4 * c + 2], a2);
      a3 = fmaf(uv.w, W1c[4 * c + 3], a3);
    }
    rows[wid][lane] = fmaxf((a0 + a1) + (a2 + a3), 0.0f);
    a0 = b2v; a1 = 0.0f; a2 = 0.0f; a3 = 0.0f;
#pragma unroll
    for (int c = 0; c < 16; ++c) {
      float4 uv = rv[c];
      a0 = fmaf(uv.x, W2c[4 * c + 0], a0);
      a1 = fmaf(uv.y, W2c[4 * c + 1], a1);
      a2 = fmaf(uv.z, W2c[4 * c + 2], a2);
      a3 = fmaf(uv.w, W2c[4 * c + 3], a3);
    }
    rows[wid][lane] = fmaxf((a0 + a1) + (a2 + a3), 0.0f);  // h (f32, stays on-chip)
    // classifier: lane c < 40 computes logit c
    float lg = lbv;
#pragma unroll
    for (int c = 0; c < 16; ++c) {
      float4 hv = rv[c];
      lg = fmaf(hv.x, LWc[4 * c + 0], lg);
      lg = fmaf(hv.y, LWc[4 * c + 1], lg);
      lg = fmaf(hv.z, LWc[4 * c + 2], lg);
      lg = fmaf(hv.w, LWc[4 * c + 3], lg);
    }
    // log_softmax over the 40 valid lanes (butterfly over all 64, invalid masked)
    float m = cl ? lg : -__builtin_inff();
#pragma unroll
    for (int o = 32; o > 0; o >>= 1) m = fmaxf(m, __shfl_xor(m, o));
    float ex = cl ? __expf(lg - m) : 0.0f;
#pragma unroll
    for (int o = 32; o > 0; o >>= 1) ex += __shfl_xor(ex, o);
    float lse = m + __logf(ex);
    if (cl) out[(size_t)node * 40 + lane] = lg - lse;
  }
}

extern "C" void kernel_launch(void* const* d_in, const int* in_sizes, int n_in,
                              void* d_out, int out_size, void* d_ws, size_t ws_size,
                              hipStream_t stream) {
  (void)n_in; (void)out_size; (void)ws_size;
  const float* x     = (const float*)d_in[0];
  const uint32* ei   = (const uint32*)d_in[1];
  const float* eattr = (const float*)d_in[2];
  const float* e_w1 = (const float*)d_in[3];
  const float* e_b1 = (const float*)d_in[4];
  const float* e_w2 = (const float*)d_in[5];
  const float* e_b2 = (const float*)d_in[6];
  const float* eps1 = (const float*)d_in[7];
  const float* m1w1 = (const float*)d_in[8];
  const float* m1b1 = (const float*)d_in[9];
  const float* m1w2 = (const float*)d_in[10];
  const float* m1b2 = (const float*)d_in[11];
  const float* eps2 = (const float*)d_in[12];
  const float* m2w1 = (const float*)d_in[13];
  const float* m2b1 = (const float*)d_in[14];
  const float* m2w2 = (const float*)d_in[15];
  const float* m2b2 = (const float*)d_in[16];
  const float* linw = (const float*)d_in[17];
  const float* linb = (const float*)d_in[18];

  const int N = in_sizes[0] / 64;
  const int E = in_sizes[1] / 2;
  const int NBKT = (N + 511) >> 9;   // 512-node buckets

  char* ws = (char*)d_ws;
  size_t off = 0;
  auto alloc = [&](size_t bytes, size_t align) {
    off = (off + align - 1) & ~(align - 1);
    size_t r = off; off += bytes; return r;
  };
  size_t oT    = alloc(64 * 4, 64);
  size_t oAB   = alloc(65 * 64 * 4, 64);
  size_t oHC   = alloc(2048 * 4, 128);                     // hist1[1024] + bCur[1024]
  size_t oOffs = alloc(((size_t)N + 1) * 4, 128);
  size_t oPay  = alloc((size_t)E * 8, 256);
  size_t oXb   = alloc((size_t)N * 64 * 2 + 32768, 256);   // bf16 gather table (+pad)
  size_t oU    = alloc((size_t)N * 64 * 2 + 32768, 1024);  // bf16 u (+pad)
  size_t oStg  = alloc((size_t)E * 8, 256);                // partition stage
  size_t oDw   = alloc((size_t)E * 2, 256);                // partition dst-local

  float*  tsS  = (float*)(ws + oT);
  uint32* ABp  = (uint32*)(ws + oAB);
  int*    h1   = (int*)(ws + oHC);
  int*    bCur = (int*)(ws + oHC + 1024 * 4);
  int*    offs = (int*)(ws + oOffs);
  int2*   pay  = (int2*)(ws + oPay);
  ushort16* xb = (ushort16*)(ws + oXb);
  ushort16* ubuf = (ushort16*)(ws + oU);
  int2*   stage = (int2*)(ws + oStg);
  unsigned short* dstw = (unsigned short*)(ws + oDw);

  hipMemsetAsync(ws + oHC, 0, 2048 * 4, stream);  // hist1 + bCur

  const int n4 = N * 64 / 4;
  const int CB = (n4 + 255) / 256;
  const int PB = (E + 2047) / 2048;

  k_setup_cast<<<65 + CB, 256, 0, stream>>>(e_w1, e_b1, e_w2, e_b2, tsS, ABp, x, xb, n4);
  k_bcount<<<1024, 256, 0, stream>>>(ei, h1, E);
  k_bpart<<<PB, 256, 0, stream>>>(ei, eattr, tsS, h1, bCur, stage, dstw, E);
  k_blocal<<<NBKT, 256, 0, stream>>>(h1, stage, dstw, offs, pay, N);
  k_conv<<<2048, 256, 0, stream>>>(xb, offs, pay, ABp, eps1, ubuf, N);
  k_mlp<<<512, 256, 0, stream>>>(ubuf, xb, m1w1, m1b1, m1w2, m1b2, N);
  k_conv<<<2048, 256, 0, stream>>>(xb, offs, pay, ABp, eps2, ubuf, N);
  k_mlp_cls<<<512, 256, 0, stream>>>(ubuf, m2w1, m2b1, m2w2, m2b2, linw, linb,
                                     (float*)d_out, N);
}

// Round 10
// 385.997 us; speedup vs baseline: 1.4625x; 1.2642x over previous
//
#include <hip/hip_runtime.h>
#include <hip/hip_bf16.h>
#include <stdint.h>

// GINE net, MI355X. Pipeline (R10):
//   k_setup_cast : blocks 0..64 = edge-MLP piecewise coeffs ABp[65][64] + sorted
//                  thresholds; blocks 65.. = f32->bf16 cast of x
//   k_bcount/k_bpart/k_blocal : CSR build (radix by dst>>9, 512-node buckets)
//   k_conv  x2   : u = bf16((1+eps)*bf16(x) + sum relu(bf16(x[src]) + a*A_p + B_p))
//                  R6-proven loop (plain 8-wide + scalar tail; R7 prefetch and R8
//                  predication both regressed -- keep compiler-scheduled form)
//   k_mlp1 / k_mlp_cls : MFMA node-MLP. R9's VALU form was LDS-PIPE-BOUND:
//                  51 ds ops/node x ~12cyc = 94us predicted vs 90us measured.
//                  MFMA tiles (16 nodes/wave, mfma_f32_16x16x32_bf16) cut DS to
//                  ~3 ops/node. Layouts per verified guide: A[m=lane&15][k=q*8+j],
//                  B[k=q*8+j][n=lane&15], C/D col=lane&15 row=q*4+reg.

typedef unsigned int uint32;
typedef unsigned short ushort16;
typedef __attribute__((ext_vector_type(8))) short bf16x8;
typedef __attribute__((ext_vector_type(4))) float f32x4;

static __device__ __forceinline__ unsigned short f2bf(float f) {
  __hip_bfloat16 h = __float2bfloat16(f);
  return *reinterpret_cast<unsigned short*>(&h);
}
static __device__ __forceinline__ float bf2f(unsigned short u) {
  return __uint_as_float(((uint32)u) << 16);
}

// ---- setup (blocks 0..64) + cast (blocks 65..) ----
__global__ __launch_bounds__(256) void k_setup_cast(
    const float* __restrict__ w1, const float* __restrict__ b1,
    const float* __restrict__ w2, const float* __restrict__ b2,
    float* __restrict__ tsS, uint32* __restrict__ ABp,
    const float* __restrict__ xin, ushort16* __restrict__ xb, int n4) {
  const int tid = threadIdx.x;
  if (blockIdx.x >= 65) {  // cast part
    int i = (blockIdx.x - 65) * 256 + tid;
    if (i < n4) {
      float4 v = ((const float4*)xin)[i];
      ushort4 o;
      o.x = f2bf(v.x); o.y = f2bf(v.y); o.z = f2bf(v.z); o.w = f2bf(v.w);
      ((ushort4*)xb)[i] = o;
    }
    return;
  }
  __shared__ float w2s[64 * 64];
  __shared__ float b2s[64];
  __shared__ float w1s[64], b1s[64], ts[64];
  __shared__ int rs[64], ms[64], vs[64];
  const int p = blockIdx.x;
  {
    const float4* g4 = (const float4*)w2;
    float4* s4 = (float4*)w2s;
    for (int i = tid; i < 64 * 16; i += 256) s4[i] = g4[i];
    if (tid < 64) b2s[tid] = b2[tid];
  }
  if (tid < 64) {
    float w = w1[tid], b = b1[tid];
    w1s[tid] = w; b1s[tid] = b;
    int v = (w != 0.0f);
    vs[tid] = v;
    ts[tid] = v ? (-b / w) : 0.0f;
  }
  __syncthreads();
  if (tid < 64) {
    float tk = ts[tid];
    int r = 0, m = 0;
    for (int k = 0; k < 64; ++k) if (vs[k]) { r += (ts[k] < tk) ? 1 : 0; m += (ts[k] == tk) ? 1 : 0; }
    rs[tid] = r; ms[tid] = m;
    if (p == 0) {
      int pos;
      if (vs[tid]) {
        int c = 0;
        for (int j = 0; j < 64; ++j)
          if (vs[j] && (ts[j] < tk || (ts[j] == tk && j < tid))) c++;
        pos = c;
      } else {
        int c = 0;
        for (int j = 0; j < 64; ++j) if (vs[j]) c++;
        for (int j = 0; j < tid; ++j) if (!vs[j]) c++;
        pos = c;
      }
      tsS[pos] = vs[tid] ? tk : __builtin_inff();
    }
  }
  __syncthreads();
  // piece p = #{thresholds < a}. Unit k active at piece p:
  //   w1>0: p >= r_k+m_k ; w1<0: p <= r_k ; w1==0: b1>0
  if (tid < 64) {
    const int j = tid;
    float accA = 0.0f, accB = b2s[j];
    for (int k = 0; k < 64; ++k) {
      bool act;
      if (vs[k]) act = (w1s[k] > 0.0f) ? (p >= rs[k] + ms[k]) : (p <= rs[k]);
      else       act = (b1s[k] > 0.0f);
      if (act) { float wv = w2s[k * 64 + j]; accA = fmaf(w1s[k], wv, accA); accB = fmaf(b1s[k], wv, accB); }
    }
    ABp[p * 64 + j] = (uint32)f2bf(accA) | ((uint32)f2bf(accB) << 16);
  }
}

static __device__ __forceinline__ bool detect_is64(const uint32* ei, int E, int tid, int* sflag) {
  if (tid < 64) {
    int lim = (E < 64) ? E : 64;
    int nz = (tid < lim) ? (ei[2 * (size_t)tid + 1] != 0u) : 0;
    nz = __any(nz);
    if (tid == 0) *sflag = !nz;
  }
  __syncthreads();
  return *sflag != 0;
}

static __device__ __forceinline__ int scan_hist(const int* __restrict__ hist1,
                                                int* bo, int* psum, int tid) {
  int v0 = hist1[tid * 4 + 0], v1 = hist1[tid * 4 + 1];
  int v2 = hist1[tid * 4 + 2], v3 = hist1[tid * 4 + 3];
  int sum = v0 + v1 + v2 + v3;
  psum[tid] = sum;
  __syncthreads();
  for (int d = 1; d < 256; d <<= 1) {
    int add = (tid >= d) ? psum[tid - d] : 0;
    __syncthreads();
    psum[tid] += add;
    __syncthreads();
  }
  int run = psum[tid] - sum;
  bo[tid * 4 + 0] = run; run += v0;
  bo[tid * 4 + 1] = run; run += v1;
  bo[tid * 4 + 2] = run; run += v2;
  bo[tid * 4 + 3] = run; run += v3;
  int total = psum[255];
  __syncthreads();
  return total;
}

// ---- CSR build: radix partition by dst>>9 (512-node buckets) ----

__global__ __launch_bounds__(256) void k_bcount(
    const uint32* __restrict__ ei, int* __restrict__ hist1, int E) {
  __shared__ int h[1024];
  __shared__ int sIs64;
  for (int i = threadIdx.x; i < 1024; i += 256) h[i] = 0;
  bool is64 = detect_is64(ei, E, threadIdx.x, &sIs64);
  for (int i = blockIdx.x * blockDim.x + threadIdx.x; i < E; i += gridDim.x * blockDim.x) {
    int dst = is64 ? (int)ei[2 * ((size_t)E + i)] : (int)ei[(size_t)E + i];
    atomicAdd(&h[dst >> 9], 1);
  }
  __syncthreads();
  for (int i = threadIdx.x; i < 1024; i += 256)
    if (h[i]) atomicAdd(&hist1[i], h[i]);
}

__global__ __launch_bounds__(256) void k_bpart(
    const uint32* __restrict__ ei, const float* __restrict__ ea,
    const float* __restrict__ tsSg, const int* __restrict__ hist1,
    int* __restrict__ bCur,
    int2* __restrict__ stage, unsigned short* __restrict__ dstw, int E) {
  __shared__ int cnt[1024];
  __shared__ int bo[1024];
  __shared__ int psum[256];
  __shared__ float tss[64];
  __shared__ int sIs64;
  const int tid = threadIdx.x;
  for (int i = tid; i < 1024; i += 256) cnt[i] = 0;
  if (tid >= 64 && tid < 128) tss[tid - 64] = tsSg[tid - 64];
  bool is64 = detect_is64(ei, E, tid, &sIs64);
  scan_hist(hist1, bo, psum, tid);
  const int base0 = blockIdx.x * 2048;
  int dstv[8], srcv[8], rk[8];
  float av[8];
#pragma unroll
  for (int e = 0; e < 8; ++e) {
    int idx = base0 + e * 256 + tid;
    if (idx < E) {
      int src, dst;
      if (is64) { src = (int)ei[2 * (size_t)idx]; dst = (int)ei[2 * ((size_t)E + idx)]; }
      else      { src = (int)ei[(size_t)idx];     dst = (int)ei[(size_t)E + idx]; }
      dstv[e] = dst; srcv[e] = src; av[e] = ea[idx];
      rk[e] = atomicAdd(&cnt[dst >> 9], 1);
    } else dstv[e] = -1;
  }
  __syncthreads();
  for (int b = tid; b < 1024; b += 256) {
    int c = cnt[b];
    cnt[b] = c ? (bo[b] + atomicAdd(&bCur[b], c)) : 0;
  }
  __syncthreads();
#pragma unroll
  for (int e = 0; e < 8; ++e) {
    if (dstv[e] < 0) continue;
    float a = av[e];
    // p = #{sorted thresholds < a}; final step admits p=64 (R4 bug, fixed R5).
    int p = 0;
#pragma unroll
    for (int s = 32; s > 0; s >>= 1) if (tss[p + s - 1] < a) p += s;
    if (tss[p] < a) ++p;
    int pos = cnt[dstv[e] >> 9] + rk[e];
    stage[pos] = make_int2(srcv[e] | (p << 20), __float_as_int(a));
    dstw[pos] = (unsigned short)(dstv[e] & 511);
  }
}

__global__ __launch_bounds__(256) void k_blocal(
    const int* __restrict__ hist1, const int2* __restrict__ stage,
    const unsigned short* __restrict__ dstw,
    int* __restrict__ offs, int2* __restrict__ pay, int N) {
  __shared__ int bo[1024];
  __shared__ int psum[256];
  __shared__ int h[512], cur[512], ps2[256];
  const int tid = threadIdx.x;
  const int b = blockIdx.x;
  int Etot = scan_hist(hist1, bo, psum, tid);
  const int s = bo[b];
  const int e2 = (b == 1023) ? Etot : bo[b + 1];
  if (b == 0 && tid == 0) offs[N] = Etot;
  h[tid] = 0; h[tid + 256] = 0;
  __syncthreads();
  for (int j = s + tid; j < e2; j += 256) atomicAdd(&h[dstw[j]], 1);
  __syncthreads();
  int a0 = h[2 * tid], a1 = h[2 * tid + 1];
  ps2[tid] = a0 + a1;
  __syncthreads();
  for (int d = 1; d < 256; d <<= 1) {
    int add = (tid >= d) ? ps2[tid - d] : 0;
    __syncthreads();
    ps2[tid] += add;
    __syncthreads();
  }
  int ex = s + ps2[tid] - (a0 + a1);
  cur[2 * tid] = ex;
  cur[2 * tid + 1] = ex + a0;
  {
    int nd0 = b * 512 + 2 * tid;
    if (nd0 < N) offs[nd0] = ex;
    if (nd0 + 1 < N) offs[nd0 + 1] = ex + a0;
  }
  __syncthreads();
  for (int j = s + tid; j < e2; j += 256) {
    int pos = atomicAdd(&cur[dstw[j]], 1);
    pay[pos] = stage[j];
  }
}

// ---- conv ----

__global__ __launch_bounds__(256) void k_conv(
    const ushort16* __restrict__ xb,
    const int* __restrict__ offs, const int2* __restrict__ pay,
    const uint32* __restrict__ ABp, const float* __restrict__ epsp,
    ushort16* __restrict__ uout, int n) {
  __shared__ uint32 ABs[65 * 64];
  {
    const uint4* g4 = (const uint4*)ABp;
    uint4* s4 = (uint4*)ABs;
    for (int i = threadIdx.x; i < 65 * 16; i += 256) s4[i] = g4[i];
  }
  __syncthreads();
  const uint32 lane = threadIdx.x & 63;
  const int wid = threadIdx.x >> 6;
  const float scale = 1.0f + epsp[0];
  for (int node = blockIdx.x * 4 + wid; node < n; node += gridDim.x * 4) {
    int s = offs[node], e = offs[node + 1];
    float acc = 0.0f;
    int i = s;
    for (; i + 7 < e; i += 8) {
      int2 q[8]; float xv[8]; uint32 ab[8];
#pragma unroll
      for (int t = 0; t < 8; ++t) q[t] = pay[i + t];
#pragma unroll
      for (int t = 0; t < 8; ++t) {
        uint32 so = ((uint32)q[t].x & 0xFFFFFu) * 64u + lane;
        xv[t] = bf2f(xb[so]);
        ab[t] = ABs[((uint32)q[t].x >> 20) * 64 + lane];
      }
#pragma unroll
      for (int t = 0; t < 8; ++t)
        acc += fmaxf(fmaf(__int_as_float(q[t].y), __uint_as_float(ab[t] << 16),
                          __uint_as_float(ab[t] & 0xffff0000u)) + xv[t], 0.0f);
    }
    for (; i < e; ++i) {
      int2 q0 = pay[i];
      uint32 so = ((uint32)q0.x & 0xFFFFFu) * 64u + lane;
      float x0 = bf2f(xb[so]);
      uint32 u0 = ABs[((uint32)q0.x >> 20) * 64 + lane];
      acc += fmaxf(fmaf(__int_as_float(q0.y), __uint_as_float(u0 << 16),
                        __uint_as_float(u0 & 0xffff0000u)) + x0, 0.0f);
    }
    float xs = bf2f(xb[(size_t)node * 64 + lane]);
    uout[(size_t)node * 64 + lane] = f2bf(fmaf(scale, xs, acc));
  }
}

// ---- MFMA node-MLP ----
// B-frag loader: row-major W[64 x OUTW]; frag element j holds bf16(W[k][ncol]),
// k = hh*32 + q*8 + j.  (B layout: n = lane&15 -> ncol, k = quad*8+j.)
template <int OUTW>
static __device__ __forceinline__ bf16x8 load_bfrag(const float* __restrict__ W,
                                                    int hh, int q, int ncol, bool valid) {
  bf16x8 f;
#pragma unroll
  for (int j = 0; j < 8; ++j) {
    int k = hh * 32 + q * 8 + j;
    f[j] = valid ? (short)f2bf(W[k * OUTW + ncol]) : (short)0;
  }
  return f;
}

#define MFMA_BF16(A, B, C) __builtin_amdgcn_mfma_f32_16x16x32_bf16((A), (B), (C), 0, 0, 0)

// mlp1: h = relu(W2^T relu(W1^T u + b1) + b2), bf16 out (conv2 gather table).
// Wave = 16-node tile. 2 MFMA per out-tile per layer (K=64 in two 32-halves).
__global__ __launch_bounds__(256) void k_mlp1(
    const unsigned short* __restrict__ uin, unsigned short* __restrict__ houtb,
    const float* __restrict__ W1, const float* __restrict__ B1,
    const float* __restrict__ W2, const float* __restrict__ B2, int n) {
  __shared__ unsigned short T[4][16 * 72];  // wave-private transpose tiles (pad 72)
  const int lane = threadIdx.x & 63;
  const int wid = threadIdx.x >> 6;
  const int cl = lane & 15;
  const int q = lane >> 4;
  bf16x8 w1f[4][2], w2f[4][2];
  float b1v[4], b2v[4];
#pragma unroll
  for (int t = 0; t < 4; ++t) {
#pragma unroll
    for (int hh = 0; hh < 2; ++hh) {
      w1f[t][hh] = load_bfrag<64>(W1, hh, q, t * 16 + cl, true);
      w2f[t][hh] = load_bfrag<64>(W2, hh, q, t * 16 + cl, true);
    }
    b1v[t] = B1[t * 16 + cl];
    b2v[t] = B2[t * 16 + cl];
  }
  unsigned short* Tw = T[wid];
  for (int node0 = blockIdx.x * 64 + wid * 16; node0 < n; node0 += gridDim.x * 64) {
    const unsigned short* ub = uin + (size_t)(node0 + cl) * 64;  // row m = cl (pad covers tail)
    bf16x8 au0 = *(const bf16x8*)(ub + q * 8);
    bf16x8 au1 = *(const bf16x8*)(ub + 32 + q * 8);
    // layer 1
#pragma unroll
    for (int t = 0; t < 4; ++t) {
      f32x4 acc = {b1v[t], b1v[t], b1v[t], b1v[t]};
      acc = MFMA_BF16(au0, w1f[t][0], acc);
      acc = MFMA_BF16(au1, w1f[t][1], acc);
#pragma unroll
      for (int r = 0; r < 4; ++r)
        Tw[(q * 4 + r) * 72 + t * 16 + cl] = f2bf(fmaxf(acc[r], 0.0f));
    }
    bf16x8 ah0 = *(const bf16x8*)&Tw[cl * 72 + q * 8];       // wave-sync LDS: same wave
    bf16x8 ah1 = *(const bf16x8*)&Tw[cl * 72 + 32 + q * 8];
    // layer 2
#pragma unroll
    for (int t = 0; t < 4; ++t) {
      f32x4 acc = {b2v[t], b2v[t], b2v[t], b2v[t]};
      acc = MFMA_BF16(ah0, w2f[t][0], acc);
      acc = MFMA_BF16(ah1, w2f[t][1], acc);
#pragma unroll
      for (int r = 0; r < 4; ++r)
        Tw[(q * 4 + r) * 72 + t * 16 + cl] = f2bf(fmaxf(acc[r], 0.0f));
    }
    // coalesced store: 4 lanes per node, 32B each
    int m2 = lane >> 2, pt = lane & 3;
    if (node0 + m2 < n) {
      bf16x8 c0 = *(const bf16x8*)&Tw[m2 * 72 + pt * 16];
      bf16x8 c1 = *(const bf16x8*)&Tw[m2 * 72 + pt * 16 + 8];
      unsigned short* ob = houtb + (size_t)(node0 + m2) * 64 + pt * 16;
      *(bf16x8*)ob = c0;
      *(bf16x8*)(ob + 8) = c1;
    }
  }
}

// mlp2 + classifier + log_softmax fused; h never leaves the CU.
__global__ __launch_bounds__(256) void k_mlp_cls(
    const unsigned short* __restrict__ uin,
    const float* __restrict__ W1, const float* __restrict__ B1,
    const float* __restrict__ W2, const float* __restrict__ B2,
    const float* __restrict__ LW, const float* __restrict__ LB,
    float* __restrict__ out, int n) {
  __shared__ unsigned short T[4][16 * 72];
  __shared__ float L[4][16 * 52];  // logits tile, pad 52
  const int lane = threadIdx.x & 63;
  const int wid = threadIdx.x >> 6;
  const int cl = lane & 15;
  const int q = lane >> 4;
  bf16x8 w1f[4][2], w2f[4][2], lwf[3][2];
  float b1v[4], b2v[4], lbv[3];
#pragma unroll
  for (int t = 0; t < 4; ++t) {
#pragma unroll
    for (int hh = 0; hh < 2; ++hh) {
      w1f[t][hh] = load_bfrag<64>(W1, hh, q, t * 16 + cl, true);
      w2f[t][hh] = load_bfrag<64>(W2, hh, q, t * 16 + cl, true);
    }
    b1v[t] = B1[t * 16 + cl];
    b2v[t] = B2[t * 16 + cl];
  }
#pragma unroll
  for (int t = 0; t < 3; ++t) {
    bool valid = (t * 16 + cl) < 40;
#pragma unroll
    for (int hh = 0; hh < 2; ++hh)
      lwf[t][hh] = load_bfrag<40>(LW, hh, q, valid ? (t * 16 + cl) : 0, valid);
    lbv[t] = valid ? LB[t * 16 + cl] : 0.0f;
  }
  unsigned short* Tw = T[wid];
  float* Lw = L[wid];
  for (int node0 = blockIdx.x * 64 + wid * 16; node0 < n; node0 += gridDim.x * 64) {
    const unsigned short* ub = uin + (size_t)(node0 + cl) * 64;
    bf16x8 au0 = *(const bf16x8*)(ub + q * 8);
    bf16x8 au1 = *(const bf16x8*)(ub + 32 + q * 8);
#pragma unroll
    for (int t = 0; t < 4; ++t) {
      f32x4 acc = {b1v[t], b1v[t], b1v[t], b1v[t]};
      acc = MFMA_BF16(au0, w1f[t][0], acc);
      acc = MFMA_BF16(au1, w1f[t][1], acc);
#pragma unroll
      for (int r = 0; r < 4; ++r)
        Tw[(q * 4 + r) * 72 + t * 16 + cl] = f2bf(fmaxf(acc[r], 0.0f));
    }
    bf16x8 ah0 = *(const bf16x8*)&Tw[cl * 72 + q * 8];
    bf16x8 ah1 = *(const bf16x8*)&Tw[cl * 72 + 32 + q * 8];
#pragma unroll
    for (int t = 0; t < 4; ++t) {
      f32x4 acc = {b2v[t], b2v[t], b2v[t], b2v[t]};
      acc = MFMA_BF16(ah0, w2f[t][0], acc);
      acc = MFMA_BF16(ah1, w2f[t][1], acc);
#pragma unroll
      for (int r = 0; r < 4; ++r)
        Tw[(q * 4 + r) * 72 + t * 16 + cl] = f2bf(fmaxf(acc[r], 0.0f));
    }
    bf16x8 g0 = *(const bf16x8*)&Tw[cl * 72 + q * 8];
    bf16x8 g1 = *(const bf16x8*)&Tw[cl * 72 + 32 + q * 8];
    // classifier: logits cols 0..47 (40..47 zero-masked weights)
#pragma unroll
    for (int t = 0; t < 3; ++t) {
      f32x4 acc = {lbv[t], lbv[t], lbv[t], lbv[t]};
      acc = MFMA_BF16(g0, lwf[t][0], acc);
      acc = MFMA_BF16(g1, lwf[t][1], acc);
#pragma unroll
      for (int r = 0; r < 4; ++r)
        Lw[(q * 4 + r) * 52 + t * 16 + cl] = acc[r];
    }
    // log_softmax: 4 lanes per node, 10 logits each; reduce via quad shfl_xor
    int m3 = lane >> 2, j3 = lane & 3;
    float lg[10];
#pragma unroll
    for (int i = 0; i < 10; ++i) lg[i] = Lw[m3 * 52 + j3 * 10 + i];
    float mx = lg[0];
#pragma unroll
    for (int i = 1; i < 10; ++i) mx = fmaxf(mx, lg[i]);
    mx = fmaxf(mx, __shfl_xor(mx, 1));
    mx = fmaxf(mx, __shfl_xor(mx, 2));
    float se = 0.0f;
#pragma unroll
    for (int i = 0; i < 10; ++i) se += __expf(lg[i] - mx);
    se += __shfl_xor(se, 1);
    se += __shfl_xor(se, 2);
    float lse = mx + __logf(se);
    if (node0 + m3 < n) {
      float* o = out + (size_t)(node0 + m3) * 40 + j3 * 10;
#pragma unroll
      for (int i = 0; i < 10; ++i) o[i] = lg[i] - lse;
    }
  }
}

extern "C" void kernel_launch(void* const* d_in, const int* in_sizes, int n_in,
                              void* d_out, int out_size, void* d_ws, size_t ws_size,
                              hipStream_t stream) {
  (void)n_in; (void)out_size; (void)ws_size;
  const float* x     = (const float*)d_in[0];
  const uint32* ei   = (const uint32*)d_in[1];
  const float* eattr = (const float*)d_in[2];
  const float* e_w1 = (const float*)d_in[3];
  const float* e_b1 = (const float*)d_in[4];
  const float* e_w2 = (const float*)d_in[5];
  const float* e_b2 = (const float*)d_in[6];
  const float* eps1 = (const float*)d_in[7];
  const float* m1w1 = (const float*)d_in[8];
  const float* m1b1 = (const float*)d_in[9];
  const float* m1w2 = (const float*)d_in[10];
  const float* m1b2 = (const float*)d_in[11];
  const float* eps2 = (const float*)d_in[12];
  const float* m2w1 = (const float*)d_in[13];
  const float* m2b1 = (const float*)d_in[14];
  const float* m2w2 = (const float*)d_in[15];
  const float* m2b2 = (const float*)d_in[16];
  const float* linw = (const float*)d_in[17];
  const float* linb = (const float*)d_in[18];

  const int N = in_sizes[0] / 64;
  const int E = in_sizes[1] / 2;
  const int NBKT = (N + 511) >> 9;

  char* ws = (char*)d_ws;
  size_t off = 0;
  auto alloc = [&](size_t bytes, size_t align) {
    off = (off + align - 1) & ~(align - 1);
    size_t r = off; off += bytes; return r;
  };
  size_t oT    = alloc(64 * 4, 64);
  size_t oAB   = alloc(65 * 64 * 4, 64);
  size_t oHC   = alloc(2048 * 4, 128);                     // hist1[1024] + bCur[1024]
  size_t oOffs = alloc(((size_t)N + 1) * 4, 128);
  size_t oPay  = alloc((size_t)E * 8, 256);
  size_t oXb   = alloc((size_t)N * 64 * 2 + 32768, 256);   // bf16 gather table (+pad)
  size_t oU    = alloc((size_t)N * 64 * 2 + 32768, 1024);  // bf16 u (+pad)
  size_t oStg  = alloc((size_t)E * 8, 256);
  size_t oDw   = alloc((size_t)E * 2, 256);

  float*  tsS  = (float*)(ws + oT);
  uint32* ABp  = (uint32*)(ws + oAB);
  int*    h1   = (int*)(ws + oHC);
  int*    bCur = (int*)(ws + oHC + 1024 * 4);
  int*    offs = (int*)(ws + oOffs);
  int2*   pay  = (int2*)(ws + oPay);
  ushort16* xb = (ushort16*)(ws + oXb);
  ushort16* ubuf = (ushort16*)(ws + oU);
  int2*   stage = (int2*)(ws + oStg);
  unsigned short* dstw = (unsigned short*)(ws + oDw);

  hipMemsetAsync(ws + oHC, 0, 2048 * 4, stream);

  const int n4 = N * 64 / 4;
  const int CB = (n4 + 255) / 256;
  const int PB = (E + 2047) / 2048;

  k_setup_cast<<<65 + CB, 256, 0, stream>>>(e_w1, e_b1, e_w2, e_b2, tsS, ABp, x, xb, n4);
  k_bcount<<<1024, 256, 0, stream>>>(ei, h1, E);
  k_bpart<<<PB, 256, 0, stream>>>(ei, eattr, tsS, h1, bCur, stage, dstw, E);
  k_blocal<<<NBKT, 256, 0, stream>>>(h1, stage, dstw, offs, pay, N);
  k_conv<<<2048, 256, 0, stream>>>(xb, offs, pay, ABp, eps1, ubuf, N);
  k_mlp1<<<512, 256, 0, stream>>>((const unsigned short*)ubuf, (unsigned short*)xb,
                                  m1w1, m1b1, m1w2, m1b2, N);
  k_conv<<<2048, 256, 0, stream>>>(xb, offs, pay, ABp, eps2, ubuf, N);
  k_mlp_cls<<<512, 256, 0, stream>>>((const unsigned short*)ubuf,
                                     m2w1, m2b1, m2w2, m2b2, linw, linb,
                                     (float*)d_out, N);
}